// Round 3
// baseline (597.017 us; speedup 1.0000x reference)
//
#include <hip/hip_runtime.h>

// MLPPredictor: score[e,c] = bias[c] + sum_k concat(h[src[e]], h[dst[e]])[k] * W[c][k]
// N_NODES=100000, E=6.4M, D=5, C=16. fp32 in/out, int32 indices.
//
// v4 theory: round 2 proved the 1.6GB workspace poison fill (~256us) is
// UNCONDITIONAL and timed (v3 used no ws, fills identical, dur unchanged).
// => workspace use is free. Also v1 (12 tx/edge) ~= v3 (2.5 tx/edge) => the
// edge kernel is NOT gather-transaction-bound; residual (~170-215us over the
// ~90us stream roofline) is per-item VALU (7 DPP + ~15 cndmask + 40 FMA) and
// register-limited latency hiding.
// => Precompute per-node partials into ws (W is edge-invariant):
//      P[n][c]    = Wb[c] + sum_k h[n,k]*Ww[c,k]        (c<16)
//      P[n][16+c] =         sum_k h[n,k]*Ww[c,5+k]
//    12.8MB table, built once (~8us). Edge kernel: out[e][c] = P[s][c] + P[d][16+c].
//    Per item (edge e, class-quad q): 2 idx loads, 2 aligned dwordx4 gathers
//    (4 lanes of the quad share the same 64B line -> 2 line-tx/edge), 4 v_add,
//    1 float4 NT store. ~10 VALU/item (was ~60), no LDS, no DPP, VGPR ~48
//    -> 8 waves/SIMD. Depth-2 pipeline on indices+gathers retained.

typedef float f4v __attribute__((ext_vector_type(4)));
typedef f4v uf4v __attribute__((aligned(4)));

constexpr int C = 16;
constexpr int D = 5;
constexpr int TWO_D = 10;
constexpr int ROW = 32;          // P row: [16 pu | 16 pv] = 128B

// ---------- table build: one thread per node ----------
__global__ __launch_bounds__(256) void build_table(
    const float* __restrict__ h, const float* __restrict__ Ww,
    const float* __restrict__ Wb, float* __restrict__ P, int nNodes)
{
    const int n = blockIdx.x * blockDim.x + threadIdx.x;
    if (n >= nNodes) return;
    float hh[D];
#pragma unroll
    for (int k = 0; k < D; ++k) hh[k] = h[(size_t)n * D + k];

    float rowbuf[ROW];
#pragma unroll
    for (int c = 0; c < C; ++c) {
        float pu = Wb[c];
        float pv = 0.0f;
#pragma unroll
        for (int k = 0; k < D; ++k) {
            pu += hh[k] * Ww[c * TWO_D + k];
            pv += hh[k] * Ww[c * TWO_D + D + k];
        }
        rowbuf[c] = pu;
        rowbuf[C + c] = pv;
    }
    f4v* dst = reinterpret_cast<f4v*>(P + (size_t)n * ROW);
#pragma unroll
    for (int j = 0; j < ROW / 4; ++j)
        dst[j] = *reinterpret_cast<const f4v*>(&rowbuf[j * 4]);
}

// ---------- edge kernel: thread g -> edge g>>2, class-quad g&3 ----------
__global__ __launch_bounds__(256) void edge_add(
    const float* __restrict__ P,
    const int* __restrict__ src,
    const int* __restrict__ dst,
    float* __restrict__ out,        // [E][16]
    int totalItems)                 // E*4
{
    const int tid0 = blockIdx.x * blockDim.x + threadIdx.x;
    const int qoff = (tid0 & 3) * 4;       // invariant: stride % 4 == 0
    const int stride = gridDim.x * blockDim.x;
    const int stride2 = stride * 2;
    const int TImax = totalItems - 1;

    auto clampE = [&](int g) { return (g < TImax ? g : TImax) >> 2; };
    auto gatherU = [&](int s) -> f4v {
        return *reinterpret_cast<const f4v*>(P + (size_t)s * ROW + qoff);
    };
    auto gatherV = [&](int d) -> f4v {
        return *reinterpret_cast<const f4v*>(P + (size_t)d * ROW + C + qoff);
    };

    // ---- pipeline prologue ----
    int eA = clampE(tid0), eB = clampE(tid0 + stride);
    int sA = __builtin_nontemporal_load(src + eA);
    int dA = __builtin_nontemporal_load(dst + eA);
    int sB = __builtin_nontemporal_load(src + eB);
    int dB = __builtin_nontemporal_load(dst + eB);
    f4v uA = gatherU(sA), vA = gatherV(dA);
    f4v uB = gatherU(sB), vB = gatherV(dB);
    {
        const int gn = tid0 + stride2;
        eA = clampE(gn); eB = clampE(gn + stride);
        sA = __builtin_nontemporal_load(src + eA);
        dA = __builtin_nontemporal_load(dst + eA);
        sB = __builtin_nontemporal_load(src + eB);
        dB = __builtin_nontemporal_load(dst + eB);
    }

    for (int g = tid0; g < totalItems; g += stride2) {
        // issue pair(i+1) gathers (indices ready from previous iteration)
        const f4v nuA = gatherU(sA), nvA = gatherV(dA);
        const f4v nuB = gatherU(sB), nvB = gatherV(dB);
        // prefetch pair(i+2) indices (clamped -> always in-bounds, no divergence)
        const int gn = g + 2 * stride2;
        eA = clampE(gn); eB = clampE(gn + stride);
        sA = __builtin_nontemporal_load(src + eA);
        dA = __builtin_nontemporal_load(dst + eA);
        sB = __builtin_nontemporal_load(src + eB);
        dB = __builtin_nontemporal_load(dst + eB);
        // consume pair(i)
        const f4v rA = uA + vA;
        __builtin_nontemporal_store(rA, reinterpret_cast<f4v*>(out + (size_t)g * 4));
        if (g + stride < totalItems) {
            const f4v rB = uB + vB;
            __builtin_nontemporal_store(rB, reinterpret_cast<f4v*>(out + (size_t)(g + stride) * 4));
        }
        uA = nuA; vA = nvA; uB = nuB; vB = nvB;
    }
}

// ---------- fallback (no/too-small workspace): v3 fused kernel ----------
template <int CTRL>
__device__ __forceinline__ float qperm(float x) {
    return __int_as_float(
        __builtin_amdgcn_mov_dpp(__float_as_int(x), CTRL, 0xF, 0xF, true));
}

__global__ __launch_bounds__(256) void edge_mlp_v3(
    const float* __restrict__ h,
    const int* __restrict__ src,
    const int* __restrict__ dst,
    const float* __restrict__ Ww,
    const float* __restrict__ Wb,
    float* __restrict__ out,
    int totalItems)
{
    __shared__ float sW[C * TWO_D + C];
    for (int i = threadIdx.x; i < C * TWO_D + C; i += blockDim.x)
        sW[i] = (i < C * TWO_D) ? Ww[i] : Wb[i - C * TWO_D];
    __syncthreads();

    const int tid0 = blockIdx.x * blockDim.x + threadIdx.x;
    const int q = tid0 & 3;
    const bool odd = (q & 1) != 0;
    const bool isV = (q >= 2);

    float w[4][TWO_D], bias[4];
#pragma unroll
    for (int j = 0; j < 4; ++j) {
        const int c = q * 4 + j;
#pragma unroll
        for (int k = 0; k < TWO_D; ++k) w[j][k] = sW[c * TWO_D + k];
        bias[j] = sW[C * TWO_D + c];
    }

    const int stride = gridDim.x * blockDim.x;
    for (int g = tid0; g < totalItems; g += stride) {
        const int e = g >> 2;
        const int r = isV ? dst[e] : src[e];
        const float* p = h + (size_t)r * D + (odd ? 1 : 0);
        const f4v m = *reinterpret_cast<const uf4v*>(p);

        const float o0 = qperm<0xB1>(m[0]);
        const float o3 = qperm<0xB1>(m[3]);
        const float a0 = odd ? o0   : m[0];
        const float a1 = odd ? m[0] : m[1];
        const float a2 = odd ? m[1] : m[2];
        const float a3 = odd ? m[2] : m[3];
        const float a4 = odd ? m[3] : o3;
        const float b0 = qperm<0x4E>(a0);
        const float b1 = qperm<0x4E>(a1);
        const float b2 = qperm<0x4E>(a2);
        const float b3 = qperm<0x4E>(a3);
        const float b4 = qperm<0x4E>(a4);

        const float u0 = isV ? b0 : a0, v0 = isV ? a0 : b0;
        const float u1 = isV ? b1 : a1, v1 = isV ? a1 : b1;
        const float u2 = isV ? b2 : a2, v2 = isV ? a2 : b2;
        const float u3 = isV ? b3 : a3, v3 = isV ? a3 : b3;
        const float u4 = isV ? b4 : a4, v4 = isV ? a4 : b4;

        f4v r4;
#pragma unroll
        for (int j = 0; j < 4; ++j) {
            float a = bias[j];
            a += u0 * w[j][0] + u1 * w[j][1] + u2 * w[j][2] + u3 * w[j][3] + u4 * w[j][4];
            a += v0 * w[j][5] + v1 * w[j][6] + v2 * w[j][7] + v3 * w[j][8] + v4 * w[j][9];
            r4[j] = a;
        }
        __builtin_nontemporal_store(r4, reinterpret_cast<f4v*>(out + (size_t)g * 4));
    }
}

extern "C" void kernel_launch(void* const* d_in, const int* in_sizes, int n_in,
                              void* d_out, int out_size, void* d_ws, size_t ws_size,
                              hipStream_t stream) {
    const float* h   = (const float*)d_in[0];   // [100000, 5]
    const int*   src = (const int*)d_in[1];     // [E]
    const int*   dst = (const int*)d_in[2];     // [E]
    const float* Ww  = (const float*)d_in[3];   // [16, 10]
    const float* Wb  = (const float*)d_in[4];   // [16]
    float* out = (float*)d_out;                 // [E, 16]

    const int E = in_sizes[1];
    const int totalItems = E * 4;               // 25.6M, fits int
    const int nNodes = in_sizes[0] / D;         // 100000

    const size_t needWs = (size_t)nNodes * ROW * sizeof(float);  // 12.8 MB
    if (d_ws != nullptr && ws_size >= needWs) {
        float* P = (float*)d_ws;
        build_table<<<(nNodes + 255) / 256, 256, 0, stream>>>(h, Ww, Wb, P, nNodes);
        edge_add<<<4096, 256, 0, stream>>>(P, src, dst, out, totalItems);
    } else {
        edge_mlp_v3<<<4096, 256, 0, stream>>>(h, src, dst, Ww, Wb, out, totalItems);
    }
}

// Round 4
// 559.191 us; speedup vs baseline: 1.0676x; 1.0676x over previous
//
#include <hip/hip_runtime.h>

// MLPPredictor: score[e,c] = bias[c] + sum_k concat(h[src[e]], h[dst[e]])[k] * W[c][k]
// N_NODES=100000, E=6.4M, D=5, C=16. fp32 in/out, int32 indices.
//
// v5 theory: timed window ~= 1.6GB ws poison fill (256us) + 410MB out poison
// (64us) + our kernel. Residuals per version: v1~250, v2~230, v3~225, v4~265us.
// v4 regressed because its 12.8MB table broke L2 residency (4MB/XCD) -> L3
// gathers; v1..v3 all ~VALU-bound (~62 VALU-ops/item: 7 DPP + ~11 cndmask +
// 40 scalar FMA). v5 cuts per-item VALU to ~33 ops:
//  * role logic (odd/isV) folded into init-time weight-register permutation
//    -> ZERO cndmask in the loop (was ~11/item)
//  * 1 cndmask + 6 DPP shuffle (send sel=odd?m3:m0 through xor1, 5x xor2)
//  * f2v packed math -> v_pk_fma_f32: 20 pk-FMA + 4 add (was 40 scalar FMA)
// Gathers stay on raw h (2MB, L2-resident per XCD): quad lane loads ONE
// dwordx4 at h+5r+(odd?1:0); depth-2 pipeline; NT idx loads + NT out stores.
// No workspace (poison fill is unconditional; ws gave nothing).

typedef float f4v __attribute__((ext_vector_type(4)));
typedef float f2v __attribute__((ext_vector_type(2)));
typedef f4v uf4v __attribute__((aligned(4)));

constexpr int C = 16;
constexpr int TWO_D = 10;
constexpr int D = 5;

// quad_perm DPP: xor1 = perm[1,0,3,2] = 0xB1 ; xor2 = perm[2,3,0,1] = 0x4E
template <int CTRL>
__device__ __forceinline__ float qperm(float x) {
    return __int_as_float(
        __builtin_amdgcn_mov_dpp(__float_as_int(x), CTRL, 0xF, 0xF, true));
}

__global__ __launch_bounds__(256) void edge_mlp_v5(
    const float* __restrict__ h,    // [N_NODES][5]
    const int* __restrict__ src,
    const int* __restrict__ dst,
    const float* __restrict__ Ww,   // [C][2D]
    const float* __restrict__ Wb,   // [C]
    float* __restrict__ out,        // [E][C]
    int totalItems)                 // E*4
{
    __shared__ float sW[C * TWO_D + C];
    for (int i = threadIdx.x; i < C * TWO_D + C; i += blockDim.x)
        sW[i] = (i < C * TWO_D) ? Ww[i] : Wb[i - C * TWO_D];
    __syncthreads();

    const int tid0 = blockIdx.x * blockDim.x + threadIdx.x;
    const int q = tid0 & 3;            // invariant: stride % 4 == 0
    const bool odd = (q & 1) != 0;     // my dwordx4 covers row elems 1..4 (else 0..3)
    const bool isV = (q >= 2);         // my row is the dst row

    // ---- role-folded weights ----
    // After shuffles, this lane's value vector is
    //   V = [m0,m1,m2,m3,mX, z0,z1,z2,z3,zX]
    // where (m,mX) = MY row in parity-permuted order pe(i) (even: 0,1,2,3 /
    // X=4; odd: 1,2,3,4 / X=0) and z = partner row (same parity => same perm).
    // Weight for V[i] is W[c][base + pe(i)]: base = isV?5:0 for my row,
    // 5-base for partner row. All role logic dies here, at init.
    int idx[10];
    {
        const int myb = isV ? D : 0;
        const int pb  = D - myb;
        const int pe0 = odd ? 1 : 0;
#pragma unroll
        for (int i = 0; i < 4; ++i) {
            idx[i]     = myb + i + pe0;
            idx[5 + i] = pb  + i + pe0;
        }
        idx[4] = myb + (odd ? 0 : 4);
        idx[9] = pb  + (odd ? 0 : 4);
    }
    f2v  wp[4][5];
    float bias[4];
#pragma unroll
    for (int c = 0; c < 4; ++c) {
        const int cc = q * 4 + c;      // my classes: q*4 .. q*4+3
#pragma unroll
        for (int p = 0; p < 5; ++p)
            wp[c][p] = f2v{sW[cc * TWO_D + idx[2 * p]],
                           sW[cc * TWO_D + idx[2 * p + 1]]};
        bias[c] = sW[C * TWO_D + cc];
    }

    const int stride  = gridDim.x * blockDim.x;
    const int stride2 = stride * 2;
    const int TImax   = totalItems - 1;

    auto clampE = [&](int g) { return (g < TImax ? g : TImax) >> 2; };
    auto loadrow = [&](int s, int d) -> f4v {
        const int r = isV ? d : s;
        const float* p = h + (size_t)r * D + (odd ? 1 : 0);
        return *reinterpret_cast<const uf4v*>(p);
    };

    auto body = [&](const f4v m, int gout, bool doStore) {
        // xor1: even lane receives partner's m3 (=row4); odd receives m0 (=row0)
        const float sel = odd ? m[3] : m[0];
        const float mX  = qperm<0xB1>(sel);
        // xor2: partner node's row (same parity -> same slot semantics)
        const float z0 = qperm<0x4E>(m[0]);
        const float z1 = qperm<0x4E>(m[1]);
        const float z2 = qperm<0x4E>(m[2]);
        const float z3 = qperm<0x4E>(m[3]);
        const float zX = qperm<0x4E>(mX);

        const f2v V0{m[0], m[1]}, V1{m[2], m[3]}, V2{mX, z0}, V3{z1, z2}, V4{z3, zX};

        f4v r;
#pragma unroll
        for (int c = 0; c < 4; ++c) {
            f2v acc{bias[c], 0.0f};
            acc += V0 * wp[c][0];
            acc += V1 * wp[c][1];
            acc += V2 * wp[c][2];
            acc += V3 * wp[c][3];
            acc += V4 * wp[c][4];
            r[c] = acc[0] + acc[1];
        }
        if (doStore)
            __builtin_nontemporal_store(r, reinterpret_cast<f4v*>(out + (size_t)gout * 4));
    };

    // ---- depth-2 software pipeline ----
    int eA = clampE(tid0), eB = clampE(tid0 + stride);
    int sA = __builtin_nontemporal_load(src + eA);
    int dA = __builtin_nontemporal_load(dst + eA);
    int sB = __builtin_nontemporal_load(src + eB);
    int dB = __builtin_nontemporal_load(dst + eB);
    f4v gA = loadrow(sA, dA);
    f4v gB = loadrow(sB, dB);
    {
        const int gn = tid0 + stride2;
        eA = clampE(gn); eB = clampE(gn + stride);
        sA = __builtin_nontemporal_load(src + eA);
        dA = __builtin_nontemporal_load(dst + eA);
        sB = __builtin_nontemporal_load(src + eB);
        dB = __builtin_nontemporal_load(dst + eB);
    }

    for (int g = tid0; g < totalItems; g += stride2) {
        // issue pair(i+1) gathers (indices ready from previous iteration)
        const f4v nA = loadrow(sA, dA);
        const f4v nB = loadrow(sB, dB);
        // prefetch pair(i+2) indices (clamped -> always in-bounds)
        const int gn = g + 2 * stride2;
        eA = clampE(gn); eB = clampE(gn + stride);
        sA = __builtin_nontemporal_load(src + eA);
        dA = __builtin_nontemporal_load(dst + eA);
        sB = __builtin_nontemporal_load(src + eB);
        dB = __builtin_nontemporal_load(dst + eB);
        // consume pair(i)
        body(gA, g, true);
        body(gB, g + stride, (g + stride) < totalItems);
        gA = nA; gB = nB;
    }
}

extern "C" void kernel_launch(void* const* d_in, const int* in_sizes, int n_in,
                              void* d_out, int out_size, void* d_ws, size_t ws_size,
                              hipStream_t stream) {
    const float* h   = (const float*)d_in[0];   // [100000, 5]
    const int*   src = (const int*)d_in[1];     // [E]
    const int*   dst = (const int*)d_in[2];     // [E]
    const float* Ww  = (const float*)d_in[3];   // [16, 10]
    const float* Wb  = (const float*)d_in[4];   // [16]
    float* out = (float*)d_out;                 // [E, 16]

    const int E = in_sizes[1];
    const int totalItems = E * 4;               // 25.6M, fits int

    edge_mlp_v5<<<4096, 256, 0, stream>>>(h, src, dst, Ww, Wb, out, totalItems);
}